// Round 6
// baseline (169.602 us; speedup 1.0000x reference)
//
#include <hip/hip_runtime.h>
#include <math.h>

#define Bb 2
#define Ll 2048
#define Dm 1024
#define Ns 16
#define Rr 64
#define Ee 96          // DT_RANK + 2*D_STATE
#define XPS 8          // K-splits for xproj GEMM (K-slice = 128)
#define BLK (Bb*Ll)    // 4096 rows
#define NTHR 256
#define CH 64          // chunks per batch-seq
#define CL 32          // chunk length

// ================= Kernel 1: xproj split-K GEMM, k-major LDS, b128 reads =================
// BM=128, 32 mtiles x 8 ksplits = 256 blocks. K-slice 128 staged in 4 sub-chunks of 32.
__global__ void __launch_bounds__(NTHR)
k_xproj(const float* __restrict__ x, const float* __restrict__ xw,
        float* __restrict__ xp_part) {
    __shared__ float xsT[32 * 132];   // [k][row], stride 132 (mult-of-4 for b128 align)
    __shared__ float wT [32 * 100];   // [k][e],   stride 100
    int bx = blockIdx.x;
    int ks = bx & 7, mt = bx >> 3;
    int i0 = mt * 128;
    int tid = threadIdx.x;
    int tx = tid & 15, ty = tid >> 4;    // thread tile: 8 rows x 6 cols

    float acc[8][6];
#pragma unroll
    for (int ii = 0; ii < 8; ++ii)
#pragma unroll
        for (int jj = 0; jj < 6; ++jj) acc[ii][jj] = 0.f;

    for (int kc = 0; kc < 4; ++kc) {
        int k0 = ks * 128 + kc * 32;
        for (int t = tid; t < 1024; t += NTHR) {         // x: 128 rows x 32 k
            int r = t >> 3, c = (t & 7) * 4;
            float4 v = *(const float4*)(x + (size_t)(i0 + r) * Dm + k0 + c);
            xsT[(c+0)*132 + r] = v.x; xsT[(c+1)*132 + r] = v.y;
            xsT[(c+2)*132 + r] = v.z; xsT[(c+3)*132 + r] = v.w;
        }
        for (int t = tid; t < 768; t += NTHR) {          // w: 96 rows x 32 k
            int r = t >> 3, c = (t & 7) * 4;
            float4 v = *(const float4*)(xw + (size_t)r * Dm + k0 + c);
            wT[(c+0)*100 + r] = v.x; wT[(c+1)*100 + r] = v.y;
            wT[(c+2)*100 + r] = v.z; wT[(c+3)*100 + r] = v.w;
        }
        __syncthreads();
#pragma unroll 8
        for (int k = 0; k < 32; ++k) {
            float xv[8], wv[6];
            *(float4*)(xv)   = *(const float4*)(xsT + k*132 + ty*8);
            *(float4*)(xv+4) = *(const float4*)(xsT + k*132 + ty*8 + 4);
            *(float2*)(wv)   = *(const float2*)(wT + k*100 + tx*6);
            *(float2*)(wv+2) = *(const float2*)(wT + k*100 + tx*6 + 2);
            *(float2*)(wv+4) = *(const float2*)(wT + k*100 + tx*6 + 4);
#pragma unroll
            for (int ii = 0; ii < 8; ++ii)
#pragma unroll
                for (int jj = 0; jj < 6; ++jj)
                    acc[ii][jj] = fmaf(xv[ii], wv[jj], acc[ii][jj]);
        }
        __syncthreads();
    }
#pragma unroll
    for (int ii = 0; ii < 8; ++ii)
#pragma unroll
        for (int jj = 0; jj < 6; ++jj)
            xp_part[((size_t)ks * BLK + (i0 + ty*8 + ii)) * Ee + tx*6 + jj] = acc[ii][jj];
}

// ================= Kernel 2: fused [split-K reduce + delta GEMM + softplus + chunk scan] =================
// BM=64 rows x BN=256 d. grid = 64 mt x 4 nt = 256 blocks. Each block owns 2 chunks (CL=32).
__global__ void __launch_bounds__(NTHR)
k_dscan(const float* __restrict__ xp_part, const float* __restrict__ dtw,
        const float* __restrict__ dtb, const float* __restrict__ x,
        const float* __restrict__ A_log,
        float* __restrict__ delta, float* __restrict__ xpBC,
        float* __restrict__ Ec, float* __restrict__ Sc) {
    __shared__ float xsT[64 * 68];     // [k][row]  (d_rank dims, reduced)     17.4 KB
    __shared__ float wdT[64 * 260];    // [k][d] during GEMM; deltaT[t][d] after  66.6 KB
    __shared__ float BCs[64 * 33];     // [row][32] reduced B/C cols            8.4 KB
    int bx = blockIdx.x;
    int nt = bx & 3, mt = bx >> 2;
    int i0 = mt * 64, j0 = nt * 256;
    int tid = threadIdx.x;
    int tx = tid & 15, ty = tid >> 4;

    // --- Phase A1: reduce xp_part cols 0..63 -> xsT (k-major) ---
    for (int t = tid; t < 1024; t += NTHR) {     // 64 rows x 16 col-groups
        int r = t >> 4, c = (t & 15) * 4;
        float4 s = make_float4(0.f, 0.f, 0.f, 0.f);
#pragma unroll
        for (int sI = 0; sI < XPS; ++sI) {
            float4 v = *(const float4*)(xp_part + ((size_t)sI * BLK + i0 + r) * Ee + c);
            s.x += v.x; s.y += v.y; s.z += v.z; s.w += v.w;
        }
        xsT[(c+0)*68 + r] = s.x; xsT[(c+1)*68 + r] = s.y;
        xsT[(c+2)*68 + r] = s.z; xsT[(c+3)*68 + r] = s.w;
    }
    // --- Phase A2: reduce cols 64..95 -> BCs, nt==0 also writes compact xpBC ---
    for (int t = tid; t < 512; t += NTHR) {      // 64 rows x 8 col-groups
        int r = t >> 3, cc = (t & 7) * 4;
        float4 s = make_float4(0.f, 0.f, 0.f, 0.f);
#pragma unroll
        for (int sI = 0; sI < XPS; ++sI) {
            float4 v = *(const float4*)(xp_part + ((size_t)sI * BLK + i0 + r) * Ee + Rr + cc);
            s.x += v.x; s.y += v.y; s.z += v.z; s.w += v.w;
        }
        BCs[r*33 + cc+0] = s.x; BCs[r*33 + cc+1] = s.y;
        BCs[r*33 + cc+2] = s.z; BCs[r*33 + cc+3] = s.w;
        if (nt == 0) *(float4*)(xpBC + (size_t)(i0 + r) * 32 + cc) = s;
    }
    // --- Phase B: stage dtw -> wdT[k][d-local] ---
    for (int t = tid; t < 4096; t += NTHR) {     // 256 d x 16 k-groups
        int r = t >> 4, c = (t & 15) * 4;
        float4 v = *(const float4*)(dtw + (size_t)(j0 + r) * Rr + c);
        wdT[(c+0)*260 + r] = v.x; wdT[(c+1)*260 + r] = v.y;
        wdT[(c+2)*260 + r] = v.z; wdT[(c+3)*260 + r] = v.w;
    }
    __syncthreads();

    // --- Phase C: GEMM 64x256, K=64; thread tile 4 rows x 16 cols at {4tx+64g} ---
    float acc[4][16];
#pragma unroll
    for (int ii = 0; ii < 4; ++ii)
#pragma unroll
        for (int jj = 0; jj < 16; ++jj) acc[ii][jj] = 0.f;
#pragma unroll 4
    for (int k = 0; k < 64; ++k) {
        float xv[4], wv[16];
        *(float4*)xv = *(const float4*)(xsT + k*68 + ty*4);
#pragma unroll
        for (int g = 0; g < 4; ++g)
            *(float4*)(wv + 4*g) = *(const float4*)(wdT + k*260 + g*64 + tx*4);
#pragma unroll
        for (int ii = 0; ii < 4; ++ii)
#pragma unroll
            for (int jj = 0; jj < 16; ++jj)
                acc[ii][jj] = fmaf(xv[ii], wv[jj], acc[ii][jj]);
    }
    __syncthreads();   // wdT dead; reuse as deltaT

    // --- Phase D: softplus epilogue -> deltaT (LDS) + global delta ---
    float* deltaT = wdT;               // [t 0..63][d-local 0..255], stride 260
#pragma unroll
    for (int g = 0; g < 4; ++g) {
        int dl0 = g*64 + tx*4;
        float4 bias = *(const float4*)(dtb + j0 + dl0);
#pragma unroll
        for (int ii = 0; ii < 4; ++ii) {
            int tloc = ty*4 + ii;
            float z0 = acc[ii][g*4+0] + bias.x, z1 = acc[ii][g*4+1] + bias.y;
            float z2 = acc[ii][g*4+2] + bias.z, z3 = acc[ii][g*4+3] + bias.w;
            float4 o;
            o.x = fmaxf(z0, 0.f) + log1pf(__expf(-fabsf(z0)));
            o.y = fmaxf(z1, 0.f) + log1pf(__expf(-fabsf(z1)));
            o.z = fmaxf(z2, 0.f) + log1pf(__expf(-fabsf(z2)));
            o.w = fmaxf(z3, 0.f) + log1pf(__expf(-fabsf(z3)));
            *(float4*)(deltaT + tloc*260 + dl0) = o;
            *(float4*)(delta + (size_t)(i0 + tloc) * Dm + j0 + dl0) = o;
        }
    }
    __syncthreads();

    // --- Phase E: chunk-local scan (h0=0) for this block's 2 chunks, 256 d's ---
    int dloc = tid, d = j0 + dloc;
    float a[Ns];
    {
        const float4* Ap = (const float4*)(A_log + (size_t)d * Ns);
        float4 a0 = Ap[0], a1 = Ap[1], a2 = Ap[2], a3 = Ap[3];
        float tmp[Ns] = {a0.x,a0.y,a0.z,a0.w, a1.x,a1.y,a1.z,a1.w,
                         a2.x,a2.y,a2.z,a2.w, a3.x,a3.y,a3.z,a3.w};
#pragma unroll
        for (int n = 0; n < Ns; ++n) a[n] = -__expf(tmp[n]);
    }
#pragma unroll
    for (int ch = 0; ch < 2; ++ch) {
        int row0 = i0 + ch * CL;
        int b = row0 >> 11, c = (row0 & (Ll - 1)) >> 5;
        float h[Ns];
#pragma unroll
        for (int n = 0; n < Ns; ++n) h[n] = 0.f;
        float sd = 0.f;
#pragma unroll 4
        for (int t = 0; t < CL; ++t) {
            int tloc = ch * CL + t;
            float dl = deltaT[tloc*260 + dloc];
            float xv = x[(size_t)(row0 + t) * Dm + d];
            float dx = dl * xv;
            sd += dl;
            const float* bp = BCs + tloc*33;          // broadcast reads
#pragma unroll
            for (int n = 0; n < Ns; ++n)
                h[n] = fmaf(__expf(dl * a[n]), h[n], dx * bp[n]);
        }
        size_t base = ((size_t)b * CH + c) * Dm + d;
        float4* Ep = (float4*)(Ec + base * Ns);
        Ep[0] = make_float4(h[0],  h[1],  h[2],  h[3]);
        Ep[1] = make_float4(h[4],  h[5],  h[6],  h[7]);
        Ep[2] = make_float4(h[8],  h[9],  h[10], h[11]);
        Ep[3] = make_float4(h[12], h[13], h[14], h[15]);
        Sc[base] = sd;
    }
}

// ================= Kernel 3: sequential combine over chunks -> Hin =================
__global__ void __launch_bounds__(NTHR)
k_combine(const float* __restrict__ Ec, const float* __restrict__ Sc,
          const float* __restrict__ A_log, float* __restrict__ Hin) {
    int gid = blockIdx.x * NTHR + threadIdx.x;   // < Bb*Dm*Ns = 32768
    int n = gid & (Ns - 1);
    int d = (gid >> 4) & (Dm - 1);
    int b = gid >> 14;
    float a = -__expf(A_log[d * Ns + n]);
    float h = 0.f;
    for (int c = 0; c < CH; ++c) {
        size_t base = ((size_t)b * CH + c) * Dm + d;
        Hin[base * Ns + n] = h;
        float P = __expf(a * Sc[base]);
        h = fmaf(P, h, Ec[base * Ns + n]);
    }
}

// ================= Kernel 4: full scan from true h_in, emit y =================
__global__ void __launch_bounds__(NTHR)
k_scan_full(const float* __restrict__ delta, const float* __restrict__ x,
            const float* __restrict__ xpBC, const float* __restrict__ A_log,
            const float* __restrict__ Dp, const float* __restrict__ Hin,
            float* __restrict__ out) {
    int bx = blockIdx.x;                          // grid = Bb*CH*4 = 512
    int dblk = bx & 3, chunk = (bx >> 2) & (CH - 1), b = bx >> 8;
    int tid = threadIdx.x;
    int d = dblk * 256 + tid;
    int row0 = b * Ll + chunk * CL;

    float a[Ns], h[Ns];
    {
        const float4* Ap = (const float4*)(A_log + (size_t)d * Ns);
        float4 a0 = Ap[0], a1 = Ap[1], a2 = Ap[2], a3 = Ap[3];
        float tmp[Ns] = {a0.x,a0.y,a0.z,a0.w, a1.x,a1.y,a1.z,a1.w,
                         a2.x,a2.y,a2.z,a2.w, a3.x,a3.y,a3.z,a3.w};
#pragma unroll
        for (int n = 0; n < Ns; ++n) a[n] = -__expf(tmp[n]);
    }
    size_t base = ((size_t)b * CH + chunk) * Dm + d;
    {
        const float4* Hp = (const float4*)(Hin + base * Ns);
        float4 h0 = Hp[0], h1 = Hp[1], h2 = Hp[2], h3 = Hp[3];
        h[0]=h0.x; h[1]=h0.y; h[2]=h0.z; h[3]=h0.w;
        h[4]=h1.x; h[5]=h1.y; h[6]=h1.z; h[7]=h1.w;
        h[8]=h2.x; h[9]=h2.y; h[10]=h2.z; h[11]=h2.w;
        h[12]=h3.x; h[13]=h3.y; h[14]=h3.z; h[15]=h3.w;
    }
    float Dval = Dp[d];

#pragma unroll 4
    for (int t = 0; t < CL; ++t) {
        size_t row = (size_t)(row0 + t);
        float dl = delta[row * Dm + d];
        float xv = x[row * Dm + d];
        const float* bp = xpBC + row * 32;        // block-uniform -> scalar loads
        float4 B0 = *(const float4*)(bp + 0),  B1 = *(const float4*)(bp + 4);
        float4 B2 = *(const float4*)(bp + 8),  B3 = *(const float4*)(bp + 12);
        float4 C0 = *(const float4*)(bp + 16), C1 = *(const float4*)(bp + 20);
        float4 C2 = *(const float4*)(bp + 24), C3 = *(const float4*)(bp + 28);
        float Bv[Ns] = {B0.x,B0.y,B0.z,B0.w, B1.x,B1.y,B1.z,B1.w,
                        B2.x,B2.y,B2.z,B2.w, B3.x,B3.y,B3.z,B3.w};
        float Cv[Ns] = {C0.x,C0.y,C0.z,C0.w, C1.x,C1.y,C1.z,C1.w,
                        C2.x,C2.y,C2.z,C2.w, C3.x,C3.y,C3.z,C3.w};
        float dx = dl * xv;
        float y = 0.f;
#pragma unroll
        for (int n = 0; n < Ns; ++n) {
            h[n] = fmaf(__expf(dl * a[n]), h[n], dx * Bv[n]);
            y = fmaf(h[n], Cv[n], y);
        }
        out[row * Dm + d] = fmaf(xv, Dval, y);
    }
}

extern "C" void kernel_launch(void* const* d_in, const int* in_sizes, int n_in,
                              void* d_out, int out_size, void* d_ws, size_t ws_size,
                              hipStream_t stream) {
    const float* x     = (const float*)d_in[0];
    const float* A_log = (const float*)d_in[1];
    const float* Dp    = (const float*)d_in[2];
    const float* xw    = (const float*)d_in[3];
    const float* dtw   = (const float*)d_in[4];
    const float* dtb   = (const float*)d_in[5];
    float* out = (float*)d_out;
    float* ws  = (float*)d_ws;

    // workspace layout (floats):
    float* delta   = ws;                          // 4,194,304
    float* xpBC    = delta   + 4194304;           //   131,072
    float* xp_part = xpBC    + 131072;            // 3,145,728 (8 * 393216)
    float* Ec      = xp_part + 3145728;           // 2,097,152 (2*64*1024*16)
    float* Sc      = Ec      + 2097152;           //   131,072
    float* Hin     = Sc      + 131072;            // 2,097,152
    // total = 11,796,480 floats = 47.2 MB

    k_xproj    <<<dim3(256), dim3(NTHR), 0, stream>>>(x, xw, xp_part);
    k_dscan    <<<dim3(256), dim3(NTHR), 0, stream>>>(xp_part, dtw, dtb, x, A_log,
                                                      delta, xpBC, Ec, Sc);
    k_combine  <<<dim3(128), dim3(NTHR), 0, stream>>>(Ec, Sc, A_log, Hin);
    k_scan_full<<<dim3(512), dim3(NTHR), 0, stream>>>(delta, x, xpBC, A_log, Dp, Hin, out);
}

// Round 7
// 167.505 us; speedup vs baseline: 1.0125x; 1.0125x over previous
//
#include <hip/hip_runtime.h>
#include <math.h>

#define Bb 2
#define Ll 2048
#define Dm 1024
#define Ns 16
#define Rr 64
#define Ee 96          // DT_RANK + 2*D_STATE
#define XPS 8          // K-splits for xproj GEMM (K-slice = 128)
#define BLK (Bb*Ll)    // 4096 rows
#define NTHR 256

// ========== Kernel 1: xproj split-K GEMM. BM=64, k-major LDS, b128/b64 fragment reads ==========
// grid = 64 mtiles x 8 ksplits = 512 blocks (2/CU). K-slice 128 staged in 4 sub-chunks of 32.
__global__ void __launch_bounds__(NTHR)
k_xproj(const float* __restrict__ x, const float* __restrict__ xw,
        float* __restrict__ xp_part) {
    __shared__ float xsT[32 * 68];    // [k][row]
    __shared__ float wT [32 * 100];   // [k][e]
    int bx = blockIdx.x;
    int ks = bx & 7, mt = bx >> 3;
    int i0 = mt * 64;
    int tid = threadIdx.x;
    int tx = tid & 15, ty = tid >> 4;    // thread tile: 4 rows x 6 cols

    float acc[4][6];
#pragma unroll
    for (int ii = 0; ii < 4; ++ii)
#pragma unroll
        for (int jj = 0; jj < 6; ++jj) acc[ii][jj] = 0.f;

    for (int kc = 0; kc < 4; ++kc) {
        int k0 = ks * 128 + kc * 32;
        for (int t = tid; t < 512; t += NTHR) {          // x: 64 rows x 32 k
            int r = t >> 3, c = (t & 7) * 4;
            float4 v = *(const float4*)(x + (size_t)(i0 + r) * Dm + k0 + c);
            xsT[(c+0)*68 + r] = v.x; xsT[(c+1)*68 + r] = v.y;
            xsT[(c+2)*68 + r] = v.z; xsT[(c+3)*68 + r] = v.w;
        }
        for (int t = tid; t < 768; t += NTHR) {          // w: 96 rows x 32 k
            int r = t >> 3, c = (t & 7) * 4;
            float4 v = *(const float4*)(xw + (size_t)r * Dm + k0 + c);
            wT[(c+0)*100 + r] = v.x; wT[(c+1)*100 + r] = v.y;
            wT[(c+2)*100 + r] = v.z; wT[(c+3)*100 + r] = v.w;
        }
        __syncthreads();
#pragma unroll 8
        for (int k = 0; k < 32; ++k) {
            float xv[4], wv[6];
            *(float4*)xv     = *(const float4*)(xsT + k*68 + ty*4);
            *(float2*)(wv)   = *(const float2*)(wT + k*100 + tx*6);
            *(float2*)(wv+2) = *(const float2*)(wT + k*100 + tx*6 + 2);
            *(float2*)(wv+4) = *(const float2*)(wT + k*100 + tx*6 + 4);
#pragma unroll
            for (int ii = 0; ii < 4; ++ii)
#pragma unroll
                for (int jj = 0; jj < 6; ++jj)
                    acc[ii][jj] = fmaf(xv[ii], wv[jj], acc[ii][jj]);
        }
        __syncthreads();
    }
#pragma unroll
    for (int ii = 0; ii < 4; ++ii)
#pragma unroll
        for (int jj = 0; jj < 6; ++jj)
            xp_part[((size_t)ks * BLK + (i0 + ty*4 + ii)) * Ee + tx*6 + jj] = acc[ii][jj];
}

// ========== Kernel 2: reduce K-splits -> xpR [bl][64] and xpBC [bl][32] ==========
__global__ void __launch_bounds__(NTHR)
k_prep(const float* __restrict__ xp_part, float* __restrict__ xpR,
       float* __restrict__ xpBC) {
    int gid = blockIdx.x * NTHR + threadIdx.x;     // 4096*24 = 98304 exactly
    int r = gid / 24, c4 = gid % 24;
    float4 s = make_float4(0.f, 0.f, 0.f, 0.f);
#pragma unroll
    for (int i = 0; i < XPS; ++i) {
        float4 v = *(const float4*)(xp_part + ((size_t)i * BLK + r) * Ee + c4 * 4);
        s.x += v.x; s.y += v.y; s.z += v.z; s.w += v.w;
    }
    if (c4 < 16) *(float4*)(xpR  + (size_t)r * Rr + c4 * 4)        = s;
    else         *(float4*)(xpBC + (size_t)r * 32 + (c4 - 16) * 4) = s;
}

// ========== Kernel 3: delta[bl][d] = softplus(xpR[bl] . dtw[d] + dtb[d]) ==========
// BM=64, BN=64 -> 64x16 = 1024 blocks (4/CU). k-major LDS, b128 fragment reads.
__global__ void __launch_bounds__(NTHR)
k_delta(const float* __restrict__ xpR, const float* __restrict__ dtw,
        const float* __restrict__ dtb, float* __restrict__ delta) {
    __shared__ float xsT[64 * 68];    // [k][row]
    __shared__ float wT [64 * 68];    // [k][d-local]
    int bx = blockIdx.x;
    int nt = bx & 15, mt = bx >> 4;
    int i0 = mt * 64, j0 = nt * 64;
    int tid = threadIdx.x, tx = tid & 15, ty = tid >> 4;

    for (int t = tid; t < 1024; t += NTHR) {
        int r = t >> 4, c = (t & 15) * 4;
        float4 v = *(const float4*)(xpR + (size_t)(i0 + r) * Rr + c);
        xsT[(c+0)*68 + r] = v.x; xsT[(c+1)*68 + r] = v.y;
        xsT[(c+2)*68 + r] = v.z; xsT[(c+3)*68 + r] = v.w;
        float4 w = *(const float4*)(dtw + (size_t)(j0 + r) * Rr + c);
        wT[(c+0)*68 + r] = w.x; wT[(c+1)*68 + r] = w.y;
        wT[(c+2)*68 + r] = w.z; wT[(c+3)*68 + r] = w.w;
    }
    __syncthreads();

    float acc[4][4];
#pragma unroll
    for (int ii = 0; ii < 4; ++ii)
#pragma unroll
        for (int jj = 0; jj < 4; ++jj) acc[ii][jj] = 0.f;
#pragma unroll 8
    for (int k = 0; k < 64; ++k) {
        float xv[4], wv[4];
        *(float4*)xv = *(const float4*)(xsT + k*68 + ty*4);
        *(float4*)wv = *(const float4*)(wT  + k*68 + tx*4);
#pragma unroll
        for (int ii = 0; ii < 4; ++ii)
#pragma unroll
            for (int jj = 0; jj < 4; ++jj)
                acc[ii][jj] = fmaf(xv[ii], wv[jj], acc[ii][jj]);
    }
    int d0 = j0 + tx * 4;
    float4 bias = *(const float4*)(dtb + d0);
#pragma unroll
    for (int ii = 0; ii < 4; ++ii) {
        int bl = i0 + ty*4 + ii;
        float z0 = acc[ii][0] + bias.x, z1 = acc[ii][1] + bias.y;
        float z2 = acc[ii][2] + bias.z, z3 = acc[ii][3] + bias.w;
        float4 o;
        o.x = fmaxf(z0, 0.f) + log1pf(__expf(-fabsf(z0)));
        o.y = fmaxf(z1, 0.f) + log1pf(__expf(-fabsf(z1)));
        o.z = fmaxf(z2, 0.f) + log1pf(__expf(-fabsf(z2)));
        o.w = fmaxf(z3, 0.f) + log1pf(__expf(-fabsf(z3)));
        *(float4*)(delta + (size_t)bl * Dm + d0) = o;
    }
}

// ---- helper: load A row into regs ----
__device__ inline void load_a(const float* __restrict__ A_log, int d, float* a) {
    const float4* Ap = (const float4*)(A_log + (size_t)d * Ns);
    float4 a0 = Ap[0], a1 = Ap[1], a2 = Ap[2], a3 = Ap[3];
    float tmp[Ns] = {a0.x,a0.y,a0.z,a0.w, a1.x,a1.y,a1.z,a1.w,
                     a2.x,a2.y,a2.z,a2.w, a3.x,a3.y,a3.z,a3.w};
#pragma unroll
    for (int n = 0; n < Ns; ++n) a[n] = -__expf(tmp[n]);
}

// ========== Kernel 4: per-chunk local scan (h0=0) -> Ec, Sc ==========
// grid = Bb * CHv * 4 (1024 for CH=128 -> 4 blocks/CU). BC chunk staged in LDS.
template<int CHv>
__global__ void __launch_bounds__(NTHR, 4)
k_scan_part(const float* __restrict__ delta, const float* __restrict__ x,
            const float* __restrict__ xpBC, const float* __restrict__ A_log,
            float* __restrict__ Ec, float* __restrict__ Sc) {
    constexpr int CLv = Ll / CHv;
    __shared__ float BCs[CLv * 32];
    int bx = blockIdx.x;
    int dblk = bx & 3, chunk = (bx >> 2) & (CHv - 1), b = bx >> 2 >> __builtin_ctz(CHv);
    int tid = threadIdx.x;
    int d = dblk * 256 + tid;
    int row0 = b * Ll + chunk * CLv;

    for (int t = tid; t < CLv * 8; t += NTHR) {
        int r = t >> 3, c = (t & 7) * 4;
        *(float4*)(BCs + r*32 + c) = *(const float4*)(xpBC + (size_t)(row0 + r) * 32 + c);
    }
    float a[Ns], h[Ns];
    load_a(A_log, d, a);
#pragma unroll
    for (int n = 0; n < Ns; ++n) h[n] = 0.f;
    float sd = 0.f;
    __syncthreads();

#pragma unroll 4
    for (int t = 0; t < CLv; ++t) {
        size_t row = (size_t)(row0 + t);
        float dl = delta[row * Dm + d];
        float xv = x[row * Dm + d];
        const float* bp = BCs + t*32;      // broadcast b128 reads
        float4 B0 = *(const float4*)(bp + 0),  B1 = *(const float4*)(bp + 4);
        float4 B2 = *(const float4*)(bp + 8),  B3 = *(const float4*)(bp + 12);
        float Bv[Ns] = {B0.x,B0.y,B0.z,B0.w, B1.x,B1.y,B1.z,B1.w,
                        B2.x,B2.y,B2.z,B2.w, B3.x,B3.y,B3.z,B3.w};
        float dx = dl * xv;
        sd += dl;
#pragma unroll
        for (int n = 0; n < Ns; ++n)
            h[n] = fmaf(__expf(dl * a[n]), h[n], dx * Bv[n]);
    }
    size_t base = ((size_t)b * CHv + chunk) * Dm + d;
    float4* Ep = (float4*)(Ec + base * Ns);
    Ep[0] = make_float4(h[0],  h[1],  h[2],  h[3]);
    Ep[1] = make_float4(h[4],  h[5],  h[6],  h[7]);
    Ep[2] = make_float4(h[8],  h[9],  h[10], h[11]);
    Ep[3] = make_float4(h[12], h[13], h[14], h[15]);
    Sc[base] = sd;
}

// ========== Kernel 5: sequential combine over chunks -> Hin ==========
template<int CHv>
__global__ void __launch_bounds__(NTHR)
k_combine(const float* __restrict__ Ec, const float* __restrict__ Sc,
          const float* __restrict__ A_log, float* __restrict__ Hin) {
    int gid = blockIdx.x * NTHR + threadIdx.x;   // < Bb*Dm*Ns = 32768
    int n = gid & (Ns - 1);
    int d = (gid >> 4) & (Dm - 1);
    int b = gid >> 14;
    float a = -__expf(A_log[d * Ns + n]);
    float h = 0.f;
    for (int c = 0; c < CHv; ++c) {
        size_t base = ((size_t)b * CHv + c) * Dm + d;
        Hin[base * Ns + n] = h;
        float P = __expf(a * Sc[base]);
        h = fmaf(P, h, Ec[base * Ns + n]);
    }
}

// ========== Kernel 6: full scan from true h_in, emit y ==========
template<int CHv>
__global__ void __launch_bounds__(NTHR, 4)
k_scan_full(const float* __restrict__ delta, const float* __restrict__ x,
            const float* __restrict__ xpBC, const float* __restrict__ A_log,
            const float* __restrict__ Dp, const float* __restrict__ Hin,
            float* __restrict__ out) {
    constexpr int CLv = Ll / CHv;
    __shared__ float BCs[CLv * 32];
    int bx = blockIdx.x;
    int dblk = bx & 3, chunk = (bx >> 2) & (CHv - 1), b = bx >> 2 >> __builtin_ctz(CHv);
    int tid = threadIdx.x;
    int d = dblk * 256 + tid;
    int row0 = b * Ll + chunk * CLv;

    for (int t = tid; t < CLv * 8; t += NTHR) {
        int r = t >> 3, c = (t & 7) * 4;
        *(float4*)(BCs + r*32 + c) = *(const float4*)(xpBC + (size_t)(row0 + r) * 32 + c);
    }
    float a[Ns], h[Ns];
    load_a(A_log, d, a);
    size_t base = ((size_t)b * CHv + chunk) * Dm + d;
    {
        const float4* Hp = (const float4*)(Hin + base * Ns);
        float4 h0 = Hp[0], h1 = Hp[1], h2 = Hp[2], h3 = Hp[3];
        h[0]=h0.x; h[1]=h0.y; h[2]=h0.z; h[3]=h0.w;
        h[4]=h1.x; h[5]=h1.y; h[6]=h1.z; h[7]=h1.w;
        h[8]=h2.x; h[9]=h2.y; h[10]=h2.z; h[11]=h2.w;
        h[12]=h3.x; h[13]=h3.y; h[14]=h3.z; h[15]=h3.w;
    }
    float Dval = Dp[d];
    __syncthreads();

#pragma unroll 4
    for (int t = 0; t < CLv; ++t) {
        size_t row = (size_t)(row0 + t);
        float dl = delta[row * Dm + d];
        float xv = x[row * Dm + d];
        const float* bp = BCs + t*32;
        float4 B0 = *(const float4*)(bp + 0),  B1 = *(const float4*)(bp + 4);
        float4 B2 = *(const float4*)(bp + 8),  B3 = *(const float4*)(bp + 12);
        float4 C0 = *(const float4*)(bp + 16), C1 = *(const float4*)(bp + 20);
        float4 C2 = *(const float4*)(bp + 24), C3 = *(const float4*)(bp + 28);
        float Bv[Ns] = {B0.x,B0.y,B0.z,B0.w, B1.x,B1.y,B1.z,B1.w,
                        B2.x,B2.y,B2.z,B2.w, B3.x,B3.y,B3.z,B3.w};
        float Cv[Ns] = {C0.x,C0.y,C0.z,C0.w, C1.x,C1.y,C1.z,C1.w,
                        C2.x,C2.y,C2.z,C2.w, C3.x,C3.y,C3.z,C3.w};
        float dx = dl * xv;
        float y = 0.f;
#pragma unroll
        for (int n = 0; n < Ns; ++n) {
            h[n] = fmaf(__expf(dl * a[n]), h[n], dx * Bv[n]);
            y = fmaf(h[n], Cv[n], y);
        }
        out[row * Dm + d] = fmaf(xv, Dval, y);
    }
}

extern "C" void kernel_launch(void* const* d_in, const int* in_sizes, int n_in,
                              void* d_out, int out_size, void* d_ws, size_t ws_size,
                              hipStream_t stream) {
    const float* x     = (const float*)d_in[0];
    const float* A_log = (const float*)d_in[1];
    const float* Dp    = (const float*)d_in[2];
    const float* xw    = (const float*)d_in[3];
    const float* dtw   = (const float*)d_in[4];
    const float* dtb   = (const float*)d_in[5];
    float* out = (float*)d_out;
    float* ws  = (float*)d_ws;

    // workspace layout (floats):
    //   xpR   : 4096*64 = 262144
    //   xpBC  : 4096*32 = 131072
    //   delta : 4194304
    //   S3 (aliased): phase1 xp_part = 8*393216 = 3145728 [dead after k_prep]
    //                 phase4+: Ec | Sc | Hin
    float* xpR     = ws;
    float* xpBC    = xpR  + 262144;
    float* delta   = xpBC + 131072;
    float* S3      = delta + 4194304;
    float* xp_part = S3;

    k_xproj<<<dim3(512),  dim3(NTHR), 0, stream>>>(x, xw, xp_part);
    k_prep <<<dim3(384),  dim3(NTHR), 0, stream>>>(xp_part, xpR, xpBC);
    k_delta<<<dim3(1024), dim3(NTHR), 0, stream>>>(xpR, dtw, dtb, delta);

    // CH=128: S3 = 4194304 + 262144 + 4194304 = 8,650,752 floats -> total 53 MB
    // CH=64 fallback: S3 = 4,325,376 -> total 35.5 MB
    size_t need128 = (size_t)(262144 + 131072 + 4194304 + 8650752) * 4;
    if (ws_size >= need128) {
        constexpr int CHv = 128;
        float* Ec  = S3;
        float* Sc  = Ec + (size_t)Bb*CHv*Dm*Ns;
        float* Hin = Sc + (size_t)Bb*CHv*Dm;
        k_scan_part<CHv><<<dim3(Bb*CHv*4), dim3(NTHR), 0, stream>>>(delta, x, xpBC, A_log, Ec, Sc);
        k_combine  <CHv><<<dim3(128),      dim3(NTHR), 0, stream>>>(Ec, Sc, A_log, Hin);
        k_scan_full<CHv><<<dim3(Bb*CHv*4), dim3(NTHR), 0, stream>>>(delta, x, xpBC, A_log, Dp, Hin, out);
    } else {
        constexpr int CHv = 64;
        float* Ec  = S3;
        float* Sc  = Ec + (size_t)Bb*CHv*Dm*Ns;
        float* Hin = Sc + (size_t)Bb*CHv*Dm;
        k_scan_part<CHv><<<dim3(Bb*CHv*4), dim3(NTHR), 0, stream>>>(delta, x, xpBC, A_log, Ec, Sc);
        k_combine  <CHv><<<dim3(128),      dim3(NTHR), 0, stream>>>(Ec, Sc, A_log, Hin);
        k_scan_full<CHv><<<dim3(Bb*CHv*4), dim3(NTHR), 0, stream>>>(delta, x, xpBC, A_log, Dp, Hin, out);
    }
}